// Round 2
// baseline (2237.377 us; speedup 1.0000x reference)
//
#include <hip/hip_runtime.h>
#include <hip/hip_bf16.h>

typedef short v8s __attribute__((ext_vector_type(8)));
typedef float v4f __attribute__((ext_vector_type(4)));

// ---------------------------------------------------------------------------
// Transpose fp32 W[k][n] (row-major, K=512 rows) -> bf16 Wt[n][k] so MFMA
// B-fragments (8 consecutive k for fixed n) are contiguous 16B global loads.
// Output-index coalesced; strided fp32 reads are L2-absorbed (tiny matrices).
// ---------------------------------------------------------------------------
__global__ void transposeW(const float* __restrict__ W,
                           __hip_bfloat16* __restrict__ Wt,
                           int N, int total) {
    int idx = blockIdx.x * 256 + threadIdx.x;
    if (idx >= total) return;
    int n = idx >> 9;      // K = 512 always
    int k = idx & 511;
    Wt[idx] = __float2bfloat16(W[k * N + n]);
}

// ---------------------------------------------------------------------------
// Fused 3-layer MLP. Block = 64 rows x 256 threads (4 waves).
// LDS x-tile: 64 rows x 512 bf16 stored as 8-elem chunks with XOR swizzle
//   addr(row, chunk) = row*512 + ((chunk ^ (row&7)) << 3)
// -> ds_read_b128 A-fragments conflict-free, tile = exactly 64 KB static LDS.
// ---------------------------------------------------------------------------

// One 512-wide layer: xbuf(64x512) = relu(xbuf @ Wt^T + b); wave owns 128 cols.
__device__ __forceinline__ void layer512(__hip_bfloat16* xbuf,
                                         const __hip_bfloat16* __restrict__ Wt,
                                         const float* __restrict__ bias,
                                         int lane, int wave, bool relu) {
    const int lrow = lane & 15;
    const int quad = lane >> 4;
    const int s = lrow & 7;
    const int wcol0 = wave * 128;

    v4f acc[4][8];
    const v4f zero = {0.f, 0.f, 0.f, 0.f};
#pragma unroll
    for (int mt = 0; mt < 4; ++mt)
#pragma unroll
        for (int nt = 0; nt < 8; ++nt) acc[mt][nt] = zero;

    const __hip_bfloat16* bp[8];
#pragma unroll
    for (int nt = 0; nt < 8; ++nt)
        bp[nt] = Wt + (size_t)(wcol0 + nt * 16 + lrow) * 512 + quad * 8;

    int rowbase[4];
#pragma unroll
    for (int mt = 0; mt < 4; ++mt) rowbase[mt] = (mt * 16 + lrow) * 512;

    for (int kk = 0; kk < 16; ++kk) {
        int sw = ((kk * 4 + quad) ^ s) << 3;   // swizzled chunk offset (elems)
        v8s a[4], b[8];
#pragma unroll
        for (int mt = 0; mt < 4; ++mt)
            a[mt] = *(const v8s*)&xbuf[rowbase[mt] + sw];
#pragma unroll
        for (int nt = 0; nt < 8; ++nt)
            b[nt] = *(const v8s*)(bp[nt] + kk * 32);
#pragma unroll
        for (int mt = 0; mt < 4; ++mt)
#pragma unroll
            for (int nt = 0; nt < 8; ++nt)
                acc[mt][nt] = __builtin_amdgcn_mfma_f32_16x16x32_bf16(
                    a[mt], b[nt], acc[mt][nt], 0, 0, 0);
    }

    __syncthreads();   // all waves done reading xbuf before overwrite
#pragma unroll
    for (int nt = 0; nt < 8; ++nt) {
        int col = wcol0 + nt * 16 + lrow;
        float bv = bias[col];
#pragma unroll
        for (int mt = 0; mt < 4; ++mt)
#pragma unroll
            for (int r = 0; r < 4; ++r) {
                int row = mt * 16 + quad * 4 + r;     // C/D: row = quad*4 + reg
                float v = acc[mt][nt][r] + bv;
                if (relu) v = fmaxf(v, 0.f);
                xbuf[row * 512 + (((col >> 3) ^ (row & 7)) << 3) + (col & 7)] =
                    __float2bfloat16(v);
            }
    }
    __syncthreads();
}

// Final layer: out(64x128 fp32) = xbuf @ Wt3^T + b3; wave owns 32 cols.
__device__ __forceinline__ void layer_out(const __hip_bfloat16* xbuf,
                                          const __hip_bfloat16* __restrict__ Wt3,
                                          const float* __restrict__ b3,
                                          float* __restrict__ out,
                                          int lane, int wave, int row0, int E) {
    const int lrow = lane & 15;
    const int quad = lane >> 4;
    const int s = lrow & 7;
    const int wcol0 = wave * 32;

    v4f acc[4][2];
    const v4f zero = {0.f, 0.f, 0.f, 0.f};
#pragma unroll
    for (int mt = 0; mt < 4; ++mt)
#pragma unroll
        for (int nt = 0; nt < 2; ++nt) acc[mt][nt] = zero;

    const __hip_bfloat16* bp[2];
#pragma unroll
    for (int nt = 0; nt < 2; ++nt)
        bp[nt] = Wt3 + (size_t)(wcol0 + nt * 16 + lrow) * 512 + quad * 8;

    int rowbase[4];
#pragma unroll
    for (int mt = 0; mt < 4; ++mt) rowbase[mt] = (mt * 16 + lrow) * 512;

    for (int kk = 0; kk < 16; ++kk) {
        int sw = ((kk * 4 + quad) ^ s) << 3;
        v8s a[4], b[2];
#pragma unroll
        for (int mt = 0; mt < 4; ++mt)
            a[mt] = *(const v8s*)&xbuf[rowbase[mt] + sw];
#pragma unroll
        for (int nt = 0; nt < 2; ++nt)
            b[nt] = *(const v8s*)(bp[nt] + kk * 32);
#pragma unroll
        for (int mt = 0; mt < 4; ++mt)
#pragma unroll
            for (int nt = 0; nt < 2; ++nt)
                acc[mt][nt] = __builtin_amdgcn_mfma_f32_16x16x32_bf16(
                    a[mt], b[nt], acc[mt][nt], 0, 0, 0);
    }

#pragma unroll
    for (int nt = 0; nt < 2; ++nt) {
        int col = wcol0 + nt * 16 + lrow;
        float bv = b3[col];
#pragma unroll
        for (int mt = 0; mt < 4; ++mt)
#pragma unroll
            for (int r = 0; r < 4; ++r) {
                int row = mt * 16 + quad * 4 + r;
                int gr = row0 + row;
                if (gr < E)
                    out[(size_t)gr * 128 + col] = acc[mt][nt][r] + bv;
            }
    }
}

__launch_bounds__(256, 2)
__global__ void fused_mlp(const float* __restrict__ src,
                          const float* __restrict__ dst,
                          const float* __restrict__ eattr,
                          const float* __restrict__ uin,
                          const int* __restrict__ batch,
                          const __hip_bfloat16* __restrict__ Wt1,
                          const float* __restrict__ b1,
                          const __hip_bfloat16* __restrict__ Wt2,
                          const float* __restrict__ b2,
                          const __hip_bfloat16* __restrict__ Wt3,
                          const float* __restrict__ b3,
                          float* __restrict__ out,
                          int E) {
    __shared__ __hip_bfloat16 xbuf[64 * 512];   // exactly 64 KB
    const int tid = threadIdx.x;
    const int lane = tid & 63;
    const int wave = tid >> 6;
    const int row0 = blockIdx.x * 64;

    // Stage x = [src | dest | edge_attr | u[batch]] : 64 rows x 512, fp32->bf16.
    // 4096 bf16 16B-chunks; per chunk: two float4 global loads + cvt + one
    // 16B LDS store. Chunk kc (0..63): segment = kc>>4, 8 floats at (kc&15)*8.
#pragma unroll
    for (int it = 0; it < 16; ++it) {
        int idx = it * 256 + tid;
        int r = idx >> 6;
        int kc = idx & 63;
        int gr = row0 + r;
        if (gr > E - 1) gr = E - 1;
        int cc = (kc & 15) * 8;
        const float* p;
        int seg = kc >> 4;
        if (seg == 0)      p = src   + (size_t)gr * 128 + cc;
        else if (seg == 1) p = dst   + (size_t)gr * 128 + cc;
        else if (seg == 2) p = eattr + (size_t)gr * 128 + cc;
        else               p = uin + (size_t)batch[gr] * 128 + cc;
        float4 v0 = ((const float4*)p)[0];
        float4 v1 = ((const float4*)p)[1];
        union { uint4 q; __hip_bfloat16 h[8]; } pk;
        pk.h[0] = __float2bfloat16(v0.x);
        pk.h[1] = __float2bfloat16(v0.y);
        pk.h[2] = __float2bfloat16(v0.z);
        pk.h[3] = __float2bfloat16(v0.w);
        pk.h[4] = __float2bfloat16(v1.x);
        pk.h[5] = __float2bfloat16(v1.y);
        pk.h[6] = __float2bfloat16(v1.z);
        pk.h[7] = __float2bfloat16(v1.w);
        *(uint4*)&xbuf[r * 512 + ((kc ^ (r & 7)) << 3)] = pk.q;
    }
    __syncthreads();

    layer512(xbuf, Wt1, b1, lane, wave, true);
    layer512(xbuf, Wt2, b2, lane, wave, true);
    layer_out(xbuf, Wt3, b3, out, lane, wave, row0, E);
}

extern "C" void kernel_launch(void* const* d_in, const int* in_sizes, int n_in,
                              void* d_out, int out_size, void* d_ws, size_t ws_size,
                              hipStream_t stream) {
    const float* src   = (const float*)d_in[0];
    const float* dst   = (const float*)d_in[1];
    const float* eattr = (const float*)d_in[2];
    const float* uin   = (const float*)d_in[3];
    const int*   batch = (const int*)d_in[4];
    const float* W1    = (const float*)d_in[5];
    const float* b1    = (const float*)d_in[6];
    const float* W2    = (const float*)d_in[7];
    const float* b2    = (const float*)d_in[8];
    const float* W3    = (const float*)d_in[9];
    const float* b3    = (const float*)d_in[10];

    const int E = in_sizes[0] / 128;

    // Workspace: transposed bf16 weights, 1.18 MB total.
    __hip_bfloat16* Wt1 = (__hip_bfloat16*)d_ws;
    __hip_bfloat16* Wt2 = Wt1 + 512 * 512;
    __hip_bfloat16* Wt3 = Wt2 + 512 * 512;

    transposeW<<<(512 * 512) / 256, 256, 0, stream>>>(W1, Wt1, 512, 512 * 512);
    transposeW<<<(512 * 512) / 256, 256, 0, stream>>>(W2, Wt2, 512, 512 * 512);
    transposeW<<<(512 * 128) / 256, 256, 0, stream>>>(W3, Wt3, 128, 512 * 128);

    int nblk = (E + 63) / 64;
    fused_mlp<<<nblk, 256, 0, stream>>>(
        src, dst, eattr, uin, batch,
        Wt1, b1, Wt2, b2, Wt3, b3,
        (float*)d_out, E);
}